// Round 1
// baseline (2133.738 us; speedup 1.0000x reference)
//
#include <hip/hip_runtime.h>
#include <hip/hip_bf16.h>
#include <math.h>

#define NN 100000
#define EE 1600000
#define HD 128
#define EPS_BN 1e-5f

// ---------------- CSR build ----------------
__global__ __launch_bounds__(256) void count_deg_k(const int* __restrict__ dst, int* __restrict__ deg) {
    int e = blockIdx.x * 256 + threadIdx.x;
    if (e < EE) atomicAdd(&deg[dst[e]], 1);
}

__global__ __launch_bounds__(256) void alloc_off_k(const int* __restrict__ deg, int* __restrict__ off,
                                                   float* __restrict__ deg_inv, int* __restrict__ counter) {
    int v = blockIdx.x * 256 + threadIdx.x;
    if (v < NN) {
        int d = deg[v];
        off[v] = atomicAdd(counter, d);
        deg_inv[v] = 1.0f / (float)(d + 1);   // +1 self-loop
    }
}

__global__ __launch_bounds__(256) void fill_csr_k(const int* __restrict__ dst, const int* __restrict__ off,
                                                  int* __restrict__ cursor, int* __restrict__ list) {
    int e = blockIdx.x * 256 + threadIdx.x;
    if (e < EE) {
        int v = dst[e];
        int p = atomicAdd(&cursor[v], 1);
        list[off[v] + p] = e;
    }
}

// ---------------- edge_attr aggregation: A[v] = sum_{e: dst=v} ea[e] ----------------
__global__ __launch_bounds__(256) void agg_ea_k(const float* __restrict__ ea, const int* __restrict__ off,
                                                const int* __restrict__ deg, const int* __restrict__ list,
                                                float* __restrict__ A) {
    int v = blockIdx.x * 4 + (threadIdx.x >> 6);
    int lane = threadIdx.x & 63;
    if (v >= NN) return;
    int o = off[v], d = deg[v];
    int c = lane * 2;
    float2 acc = make_float2(0.f, 0.f);
    for (int j = 0; j < d; ++j) {
        int eid = list[o + j];
        float2 t = *(const float2*)&ea[(size_t)eid * HD + c];
        acc.x += t.x; acc.y += t.y;
    }
    *(float2*)&A[(size_t)v * HD + c] = acc;
}

// ---------------- M_i = Wc_h @ W_i  (4 x 128x128), row-major [o][k] ----------------
__global__ __launch_bounds__(256) void make_M_k(const float* __restrict__ W0, const float* __restrict__ W1,
                                                const float* __restrict__ W2, const float* __restrict__ W3,
                                                const float* __restrict__ Wc, float* __restrict__ M) {
    int layer = blockIdx.x >> 6;
    int idx = ((blockIdx.x & 63) << 8) + threadIdx.x;
    int o = idx >> 7, k = idx & 127;
    const float* W = (layer == 0) ? W0 : (layer == 1) ? W1 : (layer == 2) ? W2 : W3;
    float s = 0.f;
    for (int j = 0; j < 128; ++j) s += Wc[o * 256 + j] * W[j * 128 + k];
    M[layer * 16384 + o * 128 + k] = s;
}

// ---------------- GEMM: out[N x 128] = Hin[N x 128] @ Wg^T, Wg row-major [o][k] stride wstride
// EPI==0: out = acc ; EPI==1: out = acc*deg_inv[row] + bias[o]
template <int EPI>
__global__ __launch_bounds__(256) void gemm128_k(const float* __restrict__ Hin, const float* __restrict__ Wg,
                                                 int wstride, float* __restrict__ out,
                                                 const float* __restrict__ deg_inv,
                                                 const float* __restrict__ bias, int nrows) {
    __shared__ float Ws[128 * 128];     // Ws[k][o]
    __shared__ float Hs[64 * 130];      // padded stride 130
    int t = threadIdx.x;
    int r0 = blockIdx.x * 64;

    // stage W (transpose to [k][o])
    {
        int o = t >> 1;
        int kh = (t & 1) << 6;
        for (int kk = 0; kk < 64; kk += 4) {
            int k = kh + kk;
            float4 w = *(const float4*)&Wg[o * wstride + k];
            Ws[(k + 0) * 128 + o] = w.x;
            Ws[(k + 1) * 128 + o] = w.y;
            Ws[(k + 2) * 128 + o] = w.z;
            Ws[(k + 3) * 128 + o] = w.w;
        }
    }
    // stage H rows
    for (int i = 0; i < 32; ++i) {
        int l = t + i * 256;
        int r = l >> 7, c = l & 127;
        int gr = r0 + r;
        Hs[r * 130 + c] = (gr < nrows) ? Hin[(size_t)gr * HD + c] : 0.0f;
    }
    __syncthreads();

    int tx = t & 15, ty = t >> 4;
    float acc[4][8];
#pragma unroll
    for (int i = 0; i < 4; ++i)
#pragma unroll
        for (int j = 0; j < 8; ++j) acc[i][j] = 0.f;

#pragma unroll 4
    for (int k = 0; k < 128; ++k) {
        float4 w0 = *(const float4*)&Ws[k * 128 + tx * 4];
        float4 w1 = *(const float4*)&Ws[k * 128 + 64 + tx * 4];
        float h0 = Hs[(ty * 4 + 0) * 130 + k];
        float h1 = Hs[(ty * 4 + 1) * 130 + k];
        float h2 = Hs[(ty * 4 + 2) * 130 + k];
        float h3 = Hs[(ty * 4 + 3) * 130 + k];
        float hh[4] = {h0, h1, h2, h3};
#pragma unroll
        for (int i = 0; i < 4; ++i) {
            acc[i][0] += hh[i] * w0.x; acc[i][1] += hh[i] * w0.y;
            acc[i][2] += hh[i] * w0.z; acc[i][3] += hh[i] * w0.w;
            acc[i][4] += hh[i] * w1.x; acc[i][5] += hh[i] * w1.y;
            acc[i][6] += hh[i] * w1.z; acc[i][7] += hh[i] * w1.w;
        }
    }

    float4 b0 = make_float4(0.f, 0.f, 0.f, 0.f), b1 = b0;
    if (EPI == 1) {
        b0 = *(const float4*)&bias[tx * 4];
        b1 = *(const float4*)&bias[64 + tx * 4];
    }
#pragma unroll
    for (int i = 0; i < 4; ++i) {
        int gr = r0 + ty * 4 + i;
        if (gr >= nrows) continue;
        float di = (EPI == 1) ? deg_inv[gr] : 1.0f;
        float4 v0, v1;
        if (EPI == 1) {
            v0 = make_float4(acc[i][0] * di + b0.x, acc[i][1] * di + b0.y,
                             acc[i][2] * di + b0.z, acc[i][3] * di + b0.w);
            v1 = make_float4(acc[i][4] * di + b1.x, acc[i][5] * di + b1.y,
                             acc[i][6] * di + b1.z, acc[i][7] * di + b1.w);
        } else {
            v0 = make_float4(acc[i][0], acc[i][1], acc[i][2], acc[i][3]);
            v1 = make_float4(acc[i][4], acc[i][5], acc[i][6], acc[i][7]);
        }
        *(float4*)&out[(size_t)gr * HD + tx * 4] = v0;
        *(float4*)&out[(size_t)gr * HD + 64 + tx * 4] = v1;
    }
}

// ---------------- neighbor sum + epilogue ----------------
// hout[v] = f( (g[v] + sum_{e:dst=v} g[src[e]]) * deg_inv[v] + U[v] + b )
template <int LAST>
__global__ __launch_bounds__(256) void agg_g_k(const float* __restrict__ g, const int* __restrict__ src_ids,
                                               const int* __restrict__ off, const int* __restrict__ deg,
                                               const int* __restrict__ list, const float* __restrict__ deg_inv,
                                               const float* __restrict__ U, const float* __restrict__ b,
                                               const float* __restrict__ bn_gamma, const float* __restrict__ bn_beta,
                                               const float* __restrict__ bn_mean, const float* __restrict__ bn_var,
                                               float* __restrict__ hout) {
    int v = blockIdx.x * 4 + (threadIdx.x >> 6);
    int lane = threadIdx.x & 63;
    if (v >= NN) return;
    int o = off[v], d = deg[v];
    int c = lane * 2;
    float2 acc = *(const float2*)&g[(size_t)v * HD + c];   // self loop
    for (int j = 0; j < d; ++j) {
        int s = src_ids[list[o + j]];
        float2 t = *(const float2*)&g[(size_t)s * HD + c];
        acc.x += t.x; acc.y += t.y;
    }
    float di = deg_inv[v];
    float2 u = *(const float2*)&U[(size_t)v * HD + c];
    float2 bb = *(const float2*)&b[c];
    float x0 = acc.x * di + u.x + bb.x;
    float x1 = acc.y * di + u.y + bb.y;
    if (!LAST) {
        float2 m  = *(const float2*)&bn_mean[c];
        float2 vv = *(const float2*)&bn_var[c];
        float2 ga = *(const float2*)&bn_gamma[c];
        float2 be = *(const float2*)&bn_beta[c];
        x0 = (x0 - m.x) * rsqrtf(vv.x + EPS_BN) * ga.x + be.x;
        x1 = (x1 - m.y) * rsqrtf(vv.y + EPS_BN) * ga.y + be.y;
        x0 = tanhf(x0);
        x1 = tanhf(x1);
    }
    *(float2*)&hout[(size_t)v * HD + c] = make_float2(x0, x1);
}

extern "C" void kernel_launch(void* const* d_in, const int* in_sizes, int n_in,
                              void* d_out, int out_size, void* d_ws, size_t ws_size,
                              hipStream_t stream) {
    const float* x   = (const float*)d_in[0];
    const int*   ei  = (const int*)d_in[1];
    const float* ea  = (const float*)d_in[2];
    const float* W0  = (const float*)d_in[3];
    const float* b0  = (const float*)d_in[4];
    const float* W1  = (const float*)d_in[5];
    const float* b1  = (const float*)d_in[6];
    const float* W2  = (const float*)d_in[7];
    const float* b2  = (const float*)d_in[8];
    const float* W3  = (const float*)d_in[9];
    const float* b3  = (const float*)d_in[10];
    const float* Wc  = (const float*)d_in[11];
    const float* bc  = (const float*)d_in[12];
    const float* bng = (const float*)d_in[13];
    const float* bnb = (const float*)d_in[14];
    const float* bnm = (const float*)d_in[15];
    const float* bnv = (const float*)d_in[16];

    const int* ei0 = ei;        // src
    const int* ei1 = ei + EE;   // dst

    char* ws = (char*)d_ws;
    // layout (byte offsets)
    int*   deg     = (int*)(ws + 0);                    // N*4 = 400000
    int*   cursor  = (int*)(ws + 400000);               // N*4
    int*   counter = (int*)(ws + 800000);               // 4 (+pad)
    int*   off     = (int*)(ws + 800256);               // N*4
    float* deg_inv = (float*)(ws + 1200256);            // N*4
    float* M       = (float*)(ws + 1600512);            // 4*16384*4 = 262144
    int*   list    = (int*)(ws + 1862656);              // E*4 = 6400000
    float* U       = (float*)(ws + 8263168);            // N*128*4 = 51200000
    float* g       = (float*)(ws + 59463168);           // N*128*4  (also used as A)
    // total ~110.7 MB
    (void)ws_size; (void)in_sizes; (void)n_in; (void)out_size;

    float* h = (float*)d_out;   // node features live in d_out between layers
    float* A = g;               // alias: A only needed before first layer GEMM

    hipMemsetAsync(ws, 0, 800256, stream);  // deg, cursor, counter

    count_deg_k<<<(EE + 255) / 256, 256, 0, stream>>>(ei1, deg);
    alloc_off_k<<<(NN + 255) / 256, 256, 0, stream>>>(deg, off, deg_inv, counter);
    fill_csr_k<<<(EE + 255) / 256, 256, 0, stream>>>(ei1, off, cursor, list);

    agg_ea_k<<<NN / 4, 256, 0, stream>>>(ea, off, deg, list, A);
    make_M_k<<<256, 256, 0, stream>>>(W0, W1, W2, W3, Wc, M);

    int gblocks = (NN + 63) / 64;
    // U = (A @ Wc_e^T) * deg_inv + bc
    gemm128_k<1><<<gblocks, 256, 0, stream>>>(A, Wc + 128, 256, U, deg_inv, bc, NN);

    const float* biases[4] = {b0, b1, b2, b3};
    for (int layer = 0; layer < 4; ++layer) {
        const float* hin = (layer == 0) ? x : h;
        gemm128_k<0><<<gblocks, 256, 0, stream>>>(hin, M + layer * 16384, 128, g,
                                                  nullptr, nullptr, NN);
        if (layer < 3) {
            agg_g_k<0><<<NN / 4, 256, 0, stream>>>(g, ei0, off, deg, list, deg_inv, U,
                                                   biases[layer], bng, bnb, bnm, bnv, h);
        } else {
            agg_g_k<1><<<NN / 4, 256, 0, stream>>>(g, ei0, off, deg, list, deg_inv, U,
                                                   biases[layer], bng, bnb, bnm, bnv, h);
        }
    }
}

// Round 2
// 1289.714 us; speedup vs baseline: 1.6544x; 1.6544x over previous
//
#include <hip/hip_runtime.h>
#include <hip/hip_bf16.h>
#include <math.h>

#define NN 100000
#define EE 1600000
#define HD 128
#define EPS_BN 1e-5f

typedef __attribute__((ext_vector_type(8))) short short8;   // 8 bf16 (4 VGPRs)
typedef __attribute__((ext_vector_type(4))) float f32x4;

__device__ inline float bf_hi(unsigned u) { return __uint_as_float(u & 0xffff0000u); }
__device__ inline float bf_lo(unsigned u) { return __uint_as_float(u << 16); }
__device__ inline unsigned pack_bf2(float x0, float x1) {
    __hip_bfloat16 a = __float2bfloat16(x0);
    __hip_bfloat16 b = __float2bfloat16(x1);
    unsigned short ua = *reinterpret_cast<unsigned short*>(&a);
    unsigned short ub = *reinterpret_cast<unsigned short*>(&b);
    return (unsigned)ua | ((unsigned)ub << 16);
}

// ---------------- CSR build ----------------
__global__ __launch_bounds__(256) void count_deg_k(const int* __restrict__ dst, int* __restrict__ deg) {
    int e = blockIdx.x * 256 + threadIdx.x;
    if (e < EE) atomicAdd(&deg[dst[e]], 1);
}

__global__ __launch_bounds__(256) void alloc_off_k(const int* __restrict__ deg, int* __restrict__ off,
                                                   float* __restrict__ deg_inv, int* __restrict__ counter) {
    int v = blockIdx.x * 256 + threadIdx.x;
    if (v < NN) {
        int d = deg[v];
        off[v] = atomicAdd(counter, d);
        deg_inv[v] = 1.0f / (float)(d + 1);   // +1 self-loop
    }
}

__global__ __launch_bounds__(256) void fill_csr_k(const int* __restrict__ src, const int* __restrict__ dst,
                                                  const int* __restrict__ off, int* __restrict__ cursor,
                                                  int* __restrict__ list_e, int* __restrict__ list_s) {
    int e = blockIdx.x * 256 + threadIdx.x;
    if (e < EE) {
        int v = dst[e];
        int p = atomicAdd(&cursor[v], 1);
        int q = off[v] + p;
        list_e[q] = e;
        list_s[q] = src[e];
    }
}

// ---------------- edge_attr aggregation: A[v] = sum_{e: dst=v} ea[e], bf16 out ----------------
__global__ __launch_bounds__(256) void agg_ea_k(const float* __restrict__ ea, const int* __restrict__ off,
                                                const int* __restrict__ deg, const int* __restrict__ list_e,
                                                unsigned* __restrict__ A) {   // A: bf16x2 packed, [N][64]
    int v = blockIdx.x * 4 + (threadIdx.x >> 6);
    int lane = threadIdx.x & 63;
    if (v >= NN) return;
    int o = off[v], d = deg[v];
    int c = lane * 2;
    float2 acc = make_float2(0.f, 0.f);
    for (int j = 0; j < d; ++j) {
        int eid = list_e[o + j];
        float2 t = *(const float2*)&ea[(size_t)eid * HD + c];
        acc.x += t.x; acc.y += t.y;
    }
    A[(size_t)v * 64 + lane] = pack_bf2(acc.x, acc.y);
}

// ---------------- weights prep: M_i = Wc_h @ W_i (bf16), Wce (bf16) ----------------
__global__ __launch_bounds__(256) void prep_w_k(const float* __restrict__ W0, const float* __restrict__ W1,
                                                const float* __restrict__ W2, const float* __restrict__ W3,
                                                const float* __restrict__ Wc,
                                                __hip_bfloat16* __restrict__ Mb,
                                                __hip_bfloat16* __restrict__ Wceb) {
    int part = blockIdx.x >> 6;                       // 0..4
    int idx = ((blockIdx.x & 63) << 8) + threadIdx.x; // 0..16383
    int o = idx >> 7, k = idx & 127;
    if (part < 4) {
        const float* W = (part == 0) ? W0 : (part == 1) ? W1 : (part == 2) ? W2 : W3;
        float s = 0.f;
        for (int j = 0; j < 128; ++j) s += Wc[o * 256 + j] * W[j * 128 + k];
        Mb[part * 16384 + idx] = __float2bfloat16(s);
    } else {
        Wceb[idx] = __float2bfloat16(Wc[o * 256 + 128 + k]);
    }
}

// ---------------- MFMA GEMM: out[N x 128](bf16) = A[N x 128] @ B^T, B row-major [o][k] bf16
// AF32: A is f32 (converted on the fly) else bf16. EPI==1: out = acc*deg_inv[row] + bias[o]
template <int AF32, int EPI>
__global__ __launch_bounds__(256) void gemm_mfma_k(const void* __restrict__ Ain,
                                                   const __hip_bfloat16* __restrict__ Bw,
                                                   __hip_bfloat16* __restrict__ out,
                                                   const float* __restrict__ deg_inv,
                                                   const float* __restrict__ bias, int nrows) {
    int wave = threadIdx.x >> 6, lane = threadIdx.x & 63;
    int r0 = blockIdx.x * 64 + wave * 16;
    int lr = lane & 15, lg = lane >> 4;

    f32x4 acc[8];
#pragma unroll
    for (int i = 0; i < 8; ++i) acc[i] = (f32x4){0.f, 0.f, 0.f, 0.f};

    int arow = r0 + lr;
    if (arow >= nrows) arow = nrows - 1;   // clamp (stores guarded)

#pragma unroll
    for (int kb = 0; kb < 4; ++kb) {
        int kofs = kb * 32 + lg * 8;
        short8 a;
        if (AF32) {
            const float* Af = (const float*)Ain + (size_t)arow * HD + kofs;
            float4 f0 = *(const float4*)Af;
            float4 f1 = *(const float4*)(Af + 4);
            union { short8 v; unsigned u[4]; } pk;
            pk.u[0] = pack_bf2(f0.x, f0.y);
            pk.u[1] = pack_bf2(f0.z, f0.w);
            pk.u[2] = pack_bf2(f1.x, f1.y);
            pk.u[3] = pack_bf2(f1.z, f1.w);
            a = pk.v;
        } else {
            a = *(const short8*)((const __hip_bfloat16*)Ain + (size_t)arow * HD + kofs);
        }
#pragma unroll
        for (int fr = 0; fr < 8; ++fr) {
            short8 b = *(const short8*)(Bw + (size_t)(fr * 16 + lr) * HD + kofs);
            acc[fr] = __builtin_amdgcn_mfma_f32_16x16x32_bf16(a, b, acc[fr], 0, 0, 0);
        }
    }

    float di[4];
    if (EPI) {
#pragma unroll
        for (int j = 0; j < 4; ++j) {
            int grow = r0 + lg * 4 + j;
            di[j] = deg_inv[(grow < nrows) ? grow : (nrows - 1)];
        }
    }
#pragma unroll
    for (int fr = 0; fr < 8; ++fr) {
        float bs = EPI ? bias[fr * 16 + lr] : 0.f;
#pragma unroll
        for (int j = 0; j < 4; ++j) {
            int grow = r0 + lg * 4 + j;
            if (grow >= nrows) continue;
            float val = acc[fr][j];
            if (EPI) val = val * di[j] + bs;
            out[(size_t)grow * HD + fr * 16 + lr] = __float2bfloat16(val);
        }
    }
}

// ---------------- neighbor sum + epilogue (bf16 tables) ----------------
// hout[v] = f( (g[v] + sum_{e:dst=v} g[src[e]]) * deg_inv[v] + U[v] + b )
template <int LAST>
__global__ __launch_bounds__(256) void agg_g_k(const unsigned* __restrict__ g,   // bf16x2 [N][64]
                                               const int* __restrict__ off, const int* __restrict__ deg,
                                               const int* __restrict__ list_s, const float* __restrict__ deg_inv,
                                               const unsigned* __restrict__ U,  // bf16x2 [N][64]
                                               const float* __restrict__ b,
                                               const float* __restrict__ bn_gamma, const float* __restrict__ bn_beta,
                                               const float* __restrict__ bn_mean, const float* __restrict__ bn_var,
                                               void* __restrict__ hout) {
    int v = blockIdx.x * 4 + (threadIdx.x >> 6);
    int lane = threadIdx.x & 63;
    if (v >= NN) return;
    int o = off[v], d = deg[v];
    int c = lane * 2;

    unsigned su = g[(size_t)v * 64 + lane];        // self loop
    float2 acc = make_float2(bf_lo(su), bf_hi(su));
    for (int j = 0; j < d; ++j) {
        int s = list_s[o + j];
        unsigned t = g[(size_t)s * 64 + lane];
        acc.x += bf_lo(t);
        acc.y += bf_hi(t);
    }
    float di = deg_inv[v];
    unsigned uu = U[(size_t)v * 64 + lane];
    float2 bb = *(const float2*)&b[c];
    float x0 = acc.x * di + bf_lo(uu) + bb.x;
    float x1 = acc.y * di + bf_hi(uu) + bb.y;
    if (!LAST) {
        float2 m  = *(const float2*)&bn_mean[c];
        float2 vv = *(const float2*)&bn_var[c];
        float2 ga = *(const float2*)&bn_gamma[c];
        float2 be = *(const float2*)&bn_beta[c];
        x0 = (x0 - m.x) * rsqrtf(vv.x + EPS_BN) * ga.x + be.x;
        x1 = (x1 - m.y) * rsqrtf(vv.y + EPS_BN) * ga.y + be.y;
        x0 = tanhf(x0);
        x1 = tanhf(x1);
        ((unsigned*)hout)[(size_t)v * 64 + lane] = pack_bf2(x0, x1);
    } else {
        *(float2*)&((float*)hout)[(size_t)v * HD + c] = make_float2(x0, x1);
    }
}

extern "C" void kernel_launch(void* const* d_in, const int* in_sizes, int n_in,
                              void* d_out, int out_size, void* d_ws, size_t ws_size,
                              hipStream_t stream) {
    const float* x   = (const float*)d_in[0];
    const int*   ei  = (const int*)d_in[1];
    const float* ea  = (const float*)d_in[2];
    const float* W0  = (const float*)d_in[3];
    const float* b0  = (const float*)d_in[4];
    const float* W1  = (const float*)d_in[5];
    const float* b1  = (const float*)d_in[6];
    const float* W2  = (const float*)d_in[7];
    const float* b2  = (const float*)d_in[8];
    const float* W3  = (const float*)d_in[9];
    const float* b3  = (const float*)d_in[10];
    const float* Wc  = (const float*)d_in[11];
    const float* bc  = (const float*)d_in[12];
    const float* bng = (const float*)d_in[13];
    const float* bnb = (const float*)d_in[14];
    const float* bnm = (const float*)d_in[15];
    const float* bnv = (const float*)d_in[16];

    const int* ei0 = ei;        // src
    const int* ei1 = ei + EE;   // dst

    char* ws = (char*)d_ws;
    int*   deg     = (int*)(ws + 0);                 // N*4
    int*   cursor  = (int*)(ws + 400000);            // N*4
    int*   counter = (int*)(ws + 800000);            // 4 (+pad)
    int*   off     = (int*)(ws + 800256);            // N*4
    float* deg_inv = (float*)(ws + 1200256);         // N*4 (+pad)
    __hip_bfloat16* Mb   = (__hip_bfloat16*)(ws + 1600512);   // 4*16384*2 = 131072
    __hip_bfloat16* Wceb = (__hip_bfloat16*)(ws + 1731584);   // 16384*2 = 32768
    int*   list_e  = (int*)(ws + 1764352);           // E*4
    int*   list_s  = (int*)(ws + 8164352);           // E*4
    unsigned* A_b  = (unsigned*)(ws + 14564352);     // N*128 bf16 = 25.6 MB
    unsigned* U_b  = (unsigned*)(ws + 40164352);     // N*128 bf16
    unsigned* g_b  = (unsigned*)(ws + 65764352);     // N*128 bf16
    unsigned* h_b  = (unsigned*)(ws + 91364352);     // N*128 bf16
    // total ~117 MB
    (void)ws_size; (void)in_sizes; (void)n_in; (void)out_size;

    hipMemsetAsync(ws, 0, 800256, stream);  // deg, cursor, counter

    count_deg_k<<<(EE + 255) / 256, 256, 0, stream>>>(ei1, deg);
    alloc_off_k<<<(NN + 255) / 256, 256, 0, stream>>>(deg, off, deg_inv, counter);
    fill_csr_k<<<(EE + 255) / 256, 256, 0, stream>>>(ei0, ei1, off, cursor, list_e, list_s);

    agg_ea_k<<<NN / 4, 256, 0, stream>>>(ea, off, deg, list_e, A_b);
    prep_w_k<<<5 * 64, 256, 0, stream>>>(W0, W1, W2, W3, Wc, Mb, Wceb);

    int gblocks = (NN + 63) / 64;
    // U = (A @ Wce^T) * deg_inv + bc   (bf16 in, bf16 out)
    gemm_mfma_k<0, 1><<<gblocks, 256, 0, stream>>>((const void*)A_b, Wceb,
                                                   (__hip_bfloat16*)U_b, deg_inv, bc, NN);

    const float* biases[4] = {b0, b1, b2, b3};
    for (int layer = 0; layer < 4; ++layer) {
        const void* hin = (layer == 0) ? (const void*)x : (const void*)h_b;
        if (layer == 0) {
            gemm_mfma_k<1, 0><<<gblocks, 256, 0, stream>>>(hin, Mb + layer * 16384,
                                                           (__hip_bfloat16*)g_b, nullptr, nullptr, NN);
        } else {
            gemm_mfma_k<0, 0><<<gblocks, 256, 0, stream>>>(hin, Mb + layer * 16384,
                                                           (__hip_bfloat16*)g_b, nullptr, nullptr, NN);
        }
        if (layer < 3) {
            agg_g_k<0><<<NN / 4, 256, 0, stream>>>(g_b, off, deg, list_s, deg_inv, U_b,
                                                   biases[layer], bng, bnb, bnm, bnv, (void*)h_b);
        } else {
            agg_g_k<1><<<NN / 4, 256, 0, stream>>>(g_b, off, deg, list_s, deg_inv, U_b,
                                                   biases[layer], bng, bnb, bnm, bnv, d_out);
        }
    }
}

// Round 3
// 963.830 us; speedup vs baseline: 2.2138x; 1.3381x over previous
//
#include <hip/hip_runtime.h>
#include <hip/hip_bf16.h>
#include <math.h>

#define NN 100000
#define EE 1600000
#define HD 128
#define EPS_BN 1e-5f

typedef __attribute__((ext_vector_type(8))) short short8;   // 8 bf16 (4 VGPRs)
typedef __attribute__((ext_vector_type(4))) float f32x4;

__device__ inline float bf_hi(unsigned u) { return __uint_as_float(u & 0xffff0000u); }
__device__ inline float bf_lo(unsigned u) { return __uint_as_float(u << 16); }
__device__ inline unsigned pack_bf2(float x0, float x1) {
    __hip_bfloat16 a = __float2bfloat16(x0);
    __hip_bfloat16 b = __float2bfloat16(x1);
    unsigned short ua = *reinterpret_cast<unsigned short*>(&a);
    unsigned short ub = *reinterpret_cast<unsigned short*>(&b);
    return (unsigned)ua | ((unsigned)ub << 16);
}

// ---------------- CSR build ----------------
__global__ __launch_bounds__(256) void count_deg_k(const int* __restrict__ dst, int* __restrict__ deg) {
    int e = blockIdx.x * 256 + threadIdx.x;
    if (e < EE) atomicAdd(&deg[dst[e]], 1);
}

__global__ __launch_bounds__(256) void alloc_off_k(const int* __restrict__ deg, int* __restrict__ off,
                                                   float* __restrict__ deg_inv, int* __restrict__ counter) {
    int v = blockIdx.x * 256 + threadIdx.x;
    if (v < NN) {
        int d = deg[v];
        off[v] = atomicAdd(counter, d);
        deg_inv[v] = 1.0f / (float)(d + 1);   // +1 self-loop
    }
}

__global__ __launch_bounds__(256) void fill_csr_k(const int* __restrict__ src, const int* __restrict__ dst,
                                                  const int* __restrict__ off, int* __restrict__ cursor,
                                                  int* __restrict__ list_e, int* __restrict__ list_s) {
    int e = blockIdx.x * 256 + threadIdx.x;
    if (e < EE) {
        int v = dst[e];
        int p = atomicAdd(&cursor[v], 1);
        int q = off[v] + p;
        list_e[q] = e;
        list_s[q] = src[e];
    }
}

// ---------------- x -> bf16 ----------------
__global__ __launch_bounds__(256) void conv_x_k(const float* __restrict__ x, unsigned* __restrict__ xb) {
    int i = blockIdx.x * 256 + threadIdx.x;     // one thread = 8 floats
    size_t base = (size_t)i * 8;
    float4 a = *(const float4*)&x[base];
    float4 b = *(const float4*)&x[base + 4];
    uint4 w;
    w.x = pack_bf2(a.x, a.y); w.y = pack_bf2(a.z, a.w);
    w.z = pack_bf2(b.x, b.y); w.w = pack_bf2(b.z, b.w);
    *(uint4*)&xb[(size_t)i * 4] = w;
}

// ---------------- edge_attr aggregation: A[v] = sum ea[e], 2 edges/wave-iter ----------------
__global__ __launch_bounds__(256) void agg_ea_k(const float* __restrict__ ea, const int* __restrict__ off,
                                                const int* __restrict__ deg, const int* __restrict__ list_e,
                                                unsigned* __restrict__ A) {   // bf16x2 packed [N][64]
    int v = blockIdx.x * 4 + (threadIdx.x >> 6);
    int lane = threadIdx.x & 63;
    int grp = lane >> 5, lr = lane & 31;     // lr covers floats lr*4..+3 of a 512B row
    if (v >= NN) return;
    int o = off[v], d = deg[v];
    float a0 = 0.f, a1 = 0.f, a2 = 0.f, a3 = 0.f;
    int nt = (d + 1) >> 1;
    for (int t = 0; t < nt; ++t) {
        int j = t * 2 + grp;
        if (j < d) {
            int e = list_e[o + j];
            float4 r = *(const float4*)&ea[(size_t)e * HD + lr * 4];
            a0 += r.x; a1 += r.y; a2 += r.z; a3 += r.w;
        }
    }
    a0 += __shfl_xor(a0, 32); a1 += __shfl_xor(a1, 32);
    a2 += __shfl_xor(a2, 32); a3 += __shfl_xor(a3, 32);
    if (grp == 0) {
        uint2 w;
        w.x = pack_bf2(a0, a1); w.y = pack_bf2(a2, a3);
        *(uint2*)&A[(size_t)v * 64 + lr * 2] = w;
    }
}

// ---------------- neighbor sum S[v] = tab[v] + sum tab[src], 4 edges/wave-iter ----------------
__global__ __launch_bounds__(256) void gather_sum_k(const unsigned* __restrict__ tab,  // bf16x2 [N][64]
                                                    const int* __restrict__ off, const int* __restrict__ deg,
                                                    const int* __restrict__ list_s,
                                                    unsigned* __restrict__ S) {
    int v = blockIdx.x * 4 + (threadIdx.x >> 6);
    int lane = threadIdx.x & 63;
    int grp = lane >> 4, lr = lane & 15;     // lr covers uints lr*4..+3 (channels lr*8..+7)
    if (v >= NN) return;
    int o = off[v], d = deg[v];
    float acc[8];
    {   // self row (count once: grp 0 only)
        uint4 r = *(const uint4*)&tab[(size_t)v * 64 + lr * 4];
        bool m = (grp == 0);
        acc[0] = m ? bf_lo(r.x) : 0.f; acc[1] = m ? bf_hi(r.x) : 0.f;
        acc[2] = m ? bf_lo(r.y) : 0.f; acc[3] = m ? bf_hi(r.y) : 0.f;
        acc[4] = m ? bf_lo(r.z) : 0.f; acc[5] = m ? bf_hi(r.z) : 0.f;
        acc[6] = m ? bf_lo(r.w) : 0.f; acc[7] = m ? bf_hi(r.w) : 0.f;
    }
    int nt = (d + 3) >> 2;
    for (int t = 0; t < nt; ++t) {
        int j = t * 4 + grp;
        if (j < d) {
            int s = list_s[o + j];
            uint4 r = *(const uint4*)&tab[(size_t)s * 64 + lr * 4];
            acc[0] += bf_lo(r.x); acc[1] += bf_hi(r.x);
            acc[2] += bf_lo(r.y); acc[3] += bf_hi(r.y);
            acc[4] += bf_lo(r.z); acc[5] += bf_hi(r.z);
            acc[6] += bf_lo(r.w); acc[7] += bf_hi(r.w);
        }
    }
#pragma unroll
    for (int i = 0; i < 8; ++i) {
        acc[i] += __shfl_xor(acc[i], 16);
        acc[i] += __shfl_xor(acc[i], 32);
    }
    if (grp == 0) {
        uint4 w;
        w.x = pack_bf2(acc[0], acc[1]); w.y = pack_bf2(acc[2], acc[3]);
        w.z = pack_bf2(acc[4], acc[5]); w.w = pack_bf2(acc[6], acc[7]);
        *(uint4*)&S[(size_t)v * 64 + lr * 4] = w;
    }
}

// ---------------- weights prep: M_i = Wc_h @ W_i (bf16), Wce (bf16) ----------------
__global__ __launch_bounds__(256) void prep_w_k(const float* __restrict__ W0, const float* __restrict__ W1,
                                                const float* __restrict__ W2, const float* __restrict__ W3,
                                                const float* __restrict__ Wc,
                                                __hip_bfloat16* __restrict__ Mb,
                                                __hip_bfloat16* __restrict__ Wceb) {
    int part = blockIdx.x >> 6;                       // 0..4
    int idx = ((blockIdx.x & 63) << 8) + threadIdx.x; // 0..16383
    int o = idx >> 7, k = idx & 127;
    if (part < 4) {
        const float* W = (part == 0) ? W0 : (part == 1) ? W1 : (part == 2) ? W2 : W3;
        float s = 0.f;
        for (int j = 0; j < 128; ++j) s += Wc[o * 256 + j] * W[j * 128 + k];
        Mb[part * 16384 + idx] = __float2bfloat16(s);
    } else {
        Wceb[idx] = __float2bfloat16(Wc[o * 256 + 128 + k]);
    }
}

// ---------------- MFMA GEMM with fused epilogue ----------------
// out = epi( (Sb @ Bw^T) ) per MODE:
//   MODE 0: val*di + bias               -> bf16 out   (U build)
//   MODE 1: tanh(BN(val*di + U + bias)) -> bf16 out   (mid layer)
//   MODE 2: val*di + U + bias           -> f32 out    (last layer)
template <int MODE>
__global__ __launch_bounds__(256) void gemm_epi_k(const __hip_bfloat16* __restrict__ Sb,
                                                  const __hip_bfloat16* __restrict__ Bw,
                                                  const __hip_bfloat16* __restrict__ Ub,
                                                  const float* __restrict__ deg_inv,
                                                  const float* __restrict__ bias,
                                                  const float* __restrict__ bng, const float* __restrict__ bnb,
                                                  const float* __restrict__ bnm, const float* __restrict__ bnv,
                                                  void* __restrict__ out) {
    int wave = threadIdx.x >> 6, lane = threadIdx.x & 63;
    int r0 = blockIdx.x * 64 + wave * 16;
    int lr = lane & 15, lg = lane >> 4;

    f32x4 acc[8];
#pragma unroll
    for (int i = 0; i < 8; ++i) acc[i] = (f32x4){0.f, 0.f, 0.f, 0.f};

    int arow = r0 + lr;
    if (arow >= NN) arow = NN - 1;   // clamp (stores guarded)

#pragma unroll
    for (int kb = 0; kb < 4; ++kb) {
        int kofs = kb * 32 + lg * 8;
        short8 a = *(const short8*)(Sb + (size_t)arow * HD + kofs);
#pragma unroll
        for (int fr = 0; fr < 8; ++fr) {
            short8 b = *(const short8*)(Bw + (size_t)(fr * 16 + lr) * HD + kofs);
            acc[fr] = __builtin_amdgcn_mfma_f32_16x16x32_bf16(a, b, acc[fr], 0, 0, 0);
        }
    }

    float di[4];
#pragma unroll
    for (int j = 0; j < 4; ++j) {
        int grow = r0 + lg * 4 + j;
        di[j] = deg_inv[(grow < NN) ? grow : (NN - 1)];
    }
#pragma unroll
    for (int fr = 0; fr < 8; ++fr) {
        int col = fr * 16 + lr;
        float bs = bias[col];
        float me = 0.f, sc = 0.f, be = 0.f;
        if (MODE == 1) {
            me = bnm[col];
            sc = bng[col] * rsqrtf(bnv[col] + EPS_BN);
            be = bnb[col];
        }
#pragma unroll
        for (int j = 0; j < 4; ++j) {
            int grow = r0 + lg * 4 + j;
            if (grow >= NN) continue;
            float val = acc[fr][j] * di[j] + bs;
            if (MODE != 0) val += __bfloat162float(Ub[(size_t)grow * HD + col]);
            if (MODE == 1) {
                val = tanhf((val - me) * sc + be);
            }
            if (MODE == 2) {
                ((float*)out)[(size_t)grow * HD + col] = val;
            } else {
                ((__hip_bfloat16*)out)[(size_t)grow * HD + col] = __float2bfloat16(val);
            }
        }
    }
}

extern "C" void kernel_launch(void* const* d_in, const int* in_sizes, int n_in,
                              void* d_out, int out_size, void* d_ws, size_t ws_size,
                              hipStream_t stream) {
    const float* x   = (const float*)d_in[0];
    const int*   ei  = (const int*)d_in[1];
    const float* ea  = (const float*)d_in[2];
    const float* W0  = (const float*)d_in[3];
    const float* b0  = (const float*)d_in[4];
    const float* W1  = (const float*)d_in[5];
    const float* b1  = (const float*)d_in[6];
    const float* W2  = (const float*)d_in[7];
    const float* b2  = (const float*)d_in[8];
    const float* W3  = (const float*)d_in[9];
    const float* b3  = (const float*)d_in[10];
    const float* Wc  = (const float*)d_in[11];
    const float* bc  = (const float*)d_in[12];
    const float* bng = (const float*)d_in[13];
    const float* bnb = (const float*)d_in[14];
    const float* bnm = (const float*)d_in[15];
    const float* bnv = (const float*)d_in[16];

    const int* ei0 = ei;        // src
    const int* ei1 = ei + EE;   // dst

    char* ws = (char*)d_ws;
    int*   deg     = (int*)(ws + 0);                 // N*4
    int*   cursor  = (int*)(ws + 400000);            // N*4
    int*   counter = (int*)(ws + 800000);            // 4 (+pad)
    int*   off     = (int*)(ws + 800256);            // N*4
    float* deg_inv = (float*)(ws + 1200256);         // N*4 (+pad)
    __hip_bfloat16* Mb   = (__hip_bfloat16*)(ws + 1600512);   // 4*16384*2
    __hip_bfloat16* Wceb = (__hip_bfloat16*)(ws + 1731584);   // 16384*2
    int*   list_e  = (int*)(ws + 1764352);           // E*4
    int*   list_s  = (int*)(ws + 8164352);           // E*4
    unsigned* A_b  = (unsigned*)(ws + 14564352);     // N*128 bf16 = 25.6 MB
    unsigned* U_b  = (unsigned*)(ws + 40164352);     // N*128 bf16
    unsigned* S_b  = (unsigned*)(ws + 65764352);     // N*128 bf16
    unsigned* h_b  = (unsigned*)(ws + 91364352);     // N*128 bf16
    unsigned* x_b  = (unsigned*)(ws + 116964352);    // N*128 bf16  -> end ~142.6 MB
    (void)ws_size; (void)in_sizes; (void)n_in; (void)out_size;

    hipMemsetAsync(ws, 0, 800256, stream);  // deg, cursor, counter

    count_deg_k<<<(EE + 255) / 256, 256, 0, stream>>>(ei1, deg);
    alloc_off_k<<<(NN + 255) / 256, 256, 0, stream>>>(deg, off, deg_inv, counter);
    fill_csr_k<<<(EE + 255) / 256, 256, 0, stream>>>(ei0, ei1, off, cursor, list_e, list_s);

    conv_x_k<<<NN * HD / (256 * 8), 256, 0, stream>>>(x, x_b);
    agg_ea_k<<<NN / 4, 256, 0, stream>>>(ea, off, deg, list_e, A_b);
    prep_w_k<<<5 * 64, 256, 0, stream>>>(W0, W1, W2, W3, Wc, Mb, Wceb);

    int gblocks = (NN + 63) / 64;
    // U = (A @ Wce^T) * deg_inv + bc
    gemm_epi_k<0><<<gblocks, 256, 0, stream>>>((const __hip_bfloat16*)A_b, Wceb, nullptr,
                                               deg_inv, bc, nullptr, nullptr, nullptr, nullptr,
                                               (void*)U_b);

    const float* biases[4] = {b0, b1, b2, b3};
    for (int layer = 0; layer < 4; ++layer) {
        const unsigned* tab = (layer == 0) ? x_b : h_b;
        gather_sum_k<<<NN / 4, 256, 0, stream>>>(tab, off, deg, list_s, S_b);
        if (layer < 3) {
            gemm_epi_k<1><<<gblocks, 256, 0, stream>>>((const __hip_bfloat16*)S_b, Mb + layer * 16384,
                                                       (const __hip_bfloat16*)U_b, deg_inv, biases[layer],
                                                       bng, bnb, bnm, bnv, (void*)h_b);
        } else {
            gemm_epi_k<2><<<gblocks, 256, 0, stream>>>((const __hip_bfloat16*)S_b, Mb + layer * 16384,
                                                       (const __hip_bfloat16*)U_b, deg_inv, biases[layer],
                                                       nullptr, nullptr, nullptr, nullptr, d_out);
        }
    }
}

// Round 5
// 888.700 us; speedup vs baseline: 2.4010x; 1.0845x over previous
//
#include <hip/hip_runtime.h>
#include <hip/hip_bf16.h>
#include <math.h>

#define NN 100000
#define EE 1600000
#define HD 128
#define EPS_BN 1e-5f

typedef __attribute__((ext_vector_type(8))) short short8;   // 8 bf16 (4 VGPRs)
typedef __attribute__((ext_vector_type(4))) float f32x4;

__device__ inline float bf_hi(unsigned u) { return __uint_as_float(u & 0xffff0000u); }
__device__ inline float bf_lo(unsigned u) { return __uint_as_float(u << 16); }
__device__ inline unsigned pack_bf2(float x0, float x1) {
    __hip_bfloat16 a = __float2bfloat16(x0);
    __hip_bfloat16 b = __float2bfloat16(x1);
    unsigned short ua = *reinterpret_cast<unsigned short*>(&a);
    unsigned short ub = *reinterpret_cast<unsigned short*>(&b);
    return (unsigned)ua | ((unsigned)ub << 16);
}

// ---------------- CSR build ----------------
__global__ __launch_bounds__(256) void count_deg_k(const int* __restrict__ dst, int* __restrict__ deg) {
    int e = blockIdx.x * 256 + threadIdx.x;
    if (e < EE) atomicAdd(&deg[dst[e]], 1);
}

__global__ __launch_bounds__(256) void alloc_off_k(const int* __restrict__ deg, int* __restrict__ off,
                                                   float* __restrict__ deg_inv, int* __restrict__ counter) {
    int v = blockIdx.x * 256 + threadIdx.x;
    if (v < NN) {
        int d = deg[v];
        off[v] = atomicAdd(counter, d);
        deg_inv[v] = 1.0f / (float)(d + 1);   // +1 self-loop
    }
}

__global__ __launch_bounds__(256) void fill_csr_k(const int* __restrict__ src, const int* __restrict__ dst,
                                                  const int* __restrict__ off, int* __restrict__ cursor,
                                                  int* __restrict__ list_e, int* __restrict__ list_s) {
    int e = blockIdx.x * 256 + threadIdx.x;
    if (e < EE) {
        int v = dst[e];
        int p = atomicAdd(&cursor[v], 1);
        int q = off[v] + p;
        list_e[q] = e;
        list_s[q] = src[e];
    }
}

// ---------------- x -> bf16 ----------------
__global__ __launch_bounds__(256) void conv_x_k(const float* __restrict__ x, unsigned* __restrict__ xb) {
    int i = blockIdx.x * 256 + threadIdx.x;     // one thread = 8 floats
    size_t base = (size_t)i * 8;
    float4 a = *(const float4*)&x[base];
    float4 b = *(const float4*)&x[base + 4];
    uint4 w;
    w.x = pack_bf2(a.x, a.y); w.y = pack_bf2(a.z, a.w);
    w.z = pack_bf2(b.x, b.y); w.w = pack_bf2(b.z, b.w);
    *(uint4*)&xb[(size_t)i * 4] = w;
}

// ---------------- edge_attr aggregation: A[v] = sum ea[e], 2 chains/grp (no shfl) ----------------
__global__ __launch_bounds__(256) void agg_ea_k(const float* __restrict__ ea, const int* __restrict__ off,
                                                const int* __restrict__ deg, const int* __restrict__ list_e,
                                                unsigned* __restrict__ A) {   // bf16x2 packed [N][64]
    int v = blockIdx.x * 4 + (threadIdx.x >> 6);
    int lane = threadIdx.x & 63;
    int grp = lane >> 5, lr = lane & 31;     // lr covers floats lr*4..+3 of a 512B row
    if (v >= NN) return;
    int o = off[v], d = deg[v];
    float a0 = 0.f, a1 = 0.f, a2 = 0.f, a3 = 0.f;
    float c0 = 0.f, c1 = 0.f, c2 = 0.f, c3 = 0.f;
    int j = grp;
    for (; j + 2 < d; j += 4) {
        int e0 = list_e[o + j];
        int e1 = list_e[o + j + 2];
        float4 r0 = *(const float4*)&ea[(size_t)e0 * HD + lr * 4];
        float4 r1 = *(const float4*)&ea[(size_t)e1 * HD + lr * 4];
        a0 += r0.x; a1 += r0.y; a2 += r0.z; a3 += r0.w;
        c0 += r1.x; c1 += r1.y; c2 += r1.z; c3 += r1.w;
    }
    for (; j < d; j += 2) {
        int e = list_e[o + j];
        float4 r = *(const float4*)&ea[(size_t)e * HD + lr * 4];
        a0 += r.x; a1 += r.y; a2 += r.z; a3 += r.w;
    }
    a0 += c0; a1 += c1; a2 += c2; a3 += c3;
    a0 += __shfl_xor(a0, 32); a1 += __shfl_xor(a1, 32);
    a2 += __shfl_xor(a2, 32); a3 += __shfl_xor(a3, 32);
    if (grp == 0) {
        uint2 w;
        w.x = pack_bf2(a0, a1); w.y = pack_bf2(a2, a3);
        *(uint2*)&A[(size_t)v * 64 + lr * 2] = w;
    }
}

// ---------------- neighbor sum S[v] = tab[v] + sum tab[src], 2 chains/grp (no shfl) ----------------
__global__ __launch_bounds__(256) void gather_sum_k(const unsigned* __restrict__ tab,  // bf16x2 [N][64]
                                                    const int* __restrict__ off, const int* __restrict__ deg,
                                                    const int* __restrict__ list_s,
                                                    unsigned* __restrict__ S) {
    int v = blockIdx.x * 4 + (threadIdx.x >> 6);
    int lane = threadIdx.x & 63;
    int grp = lane >> 4, lr = lane & 15;     // lr covers uints lr*4..+3 (channels lr*8..+7)
    if (v >= NN) return;
    int o = off[v], d = deg[v];
    float acc[8];
    {   // self row (count once: grp 0 only)
        uint4 r = *(const uint4*)&tab[(size_t)v * 64 + lr * 4];
        bool m = (grp == 0);
        acc[0] = m ? bf_lo(r.x) : 0.f; acc[1] = m ? bf_hi(r.x) : 0.f;
        acc[2] = m ? bf_lo(r.y) : 0.f; acc[3] = m ? bf_hi(r.y) : 0.f;
        acc[4] = m ? bf_lo(r.z) : 0.f; acc[5] = m ? bf_hi(r.z) : 0.f;
        acc[6] = m ? bf_lo(r.w) : 0.f; acc[7] = m ? bf_hi(r.w) : 0.f;
    }
    int j = grp;
    for (; j + 4 < d; j += 8) {
        int s0 = list_s[o + j];
        int s1 = list_s[o + j + 4];
        uint4 r0 = *(const uint4*)&tab[(size_t)s0 * 64 + lr * 4];
        uint4 r1 = *(const uint4*)&tab[(size_t)s1 * 64 + lr * 4];
        acc[0] += bf_lo(r0.x) + bf_lo(r1.x); acc[1] += bf_hi(r0.x) + bf_hi(r1.x);
        acc[2] += bf_lo(r0.y) + bf_lo(r1.y); acc[3] += bf_hi(r0.y) + bf_hi(r1.y);
        acc[4] += bf_lo(r0.z) + bf_lo(r1.z); acc[5] += bf_hi(r0.z) + bf_hi(r1.z);
        acc[6] += bf_lo(r0.w) + bf_lo(r1.w); acc[7] += bf_hi(r0.w) + bf_hi(r1.w);
    }
    for (; j < d; j += 4) {
        int s = list_s[o + j];
        uint4 r = *(const uint4*)&tab[(size_t)s * 64 + lr * 4];
        acc[0] += bf_lo(r.x); acc[1] += bf_hi(r.x);
        acc[2] += bf_lo(r.y); acc[3] += bf_hi(r.y);
        acc[4] += bf_lo(r.z); acc[5] += bf_hi(r.z);
        acc[6] += bf_lo(r.w); acc[7] += bf_hi(r.w);
    }
#pragma unroll
    for (int i = 0; i < 8; ++i) {
        acc[i] += __shfl_xor(acc[i], 16);
        acc[i] += __shfl_xor(acc[i], 32);
    }
    if (grp == 0) {
        uint4 w;
        w.x = pack_bf2(acc[0], acc[1]); w.y = pack_bf2(acc[2], acc[3]);
        w.z = pack_bf2(acc[4], acc[5]); w.w = pack_bf2(acc[6], acc[7]);
        *(uint4*)&S[(size_t)v * 64 + lr * 4] = w;
    }
}

// ---------------- weights prep: M_i = Wc_h @ W_i (bf16), Wce (bf16) ----------------
__global__ __launch_bounds__(256) void prep_w_k(const float* __restrict__ W0, const float* __restrict__ W1,
                                                const float* __restrict__ W2, const float* __restrict__ W3,
                                                const float* __restrict__ Wc,
                                                __hip_bfloat16* __restrict__ Mb,
                                                __hip_bfloat16* __restrict__ Wceb) {
    int part = blockIdx.x >> 6;                       // 0..4
    int idx = ((blockIdx.x & 63) << 8) + threadIdx.x; // 0..16383
    int o = idx >> 7, k = idx & 127;
    if (part < 4) {
        const float* W = (part == 0) ? W0 : (part == 1) ? W1 : (part == 2) ? W2 : W3;
        float s = 0.f;
        for (int j = 0; j < 128; ++j) s += Wc[o * 256 + j] * W[j * 128 + k];
        Mb[part * 16384 + idx] = __float2bfloat16(s);
    } else {
        Wceb[idx] = __float2bfloat16(Wc[o * 256 + 128 + k]);
    }
}

// ---------------- MFMA GEMM with fused epilogue ----------------
// out = epi( (Sb @ Bw^T) ) per MODE:
//   MODE 0: val*di + bias               -> bf16 out   (U build)
//   MODE 1: tanh(BN(val*di + U + bias)) -> bf16 out   (mid layer)
//   MODE 2: val*di + U + bias           -> f32 out    (last layer)
template <int MODE>
__global__ __launch_bounds__(256) void gemm_epi_k(const __hip_bfloat16* __restrict__ Sb,
                                                  const __hip_bfloat16* __restrict__ Bw,
                                                  const __hip_bfloat16* __restrict__ Ub,
                                                  const float* __restrict__ deg_inv,
                                                  const float* __restrict__ bias,
                                                  const float* __restrict__ bng, const float* __restrict__ bnb,
                                                  const float* __restrict__ bnm, const float* __restrict__ bnv,
                                                  void* __restrict__ out) {
    int wave = threadIdx.x >> 6, lane = threadIdx.x & 63;
    int r0 = blockIdx.x * 64 + wave * 16;
    int lr = lane & 15, lg = lane >> 4;

    f32x4 acc[8];
#pragma unroll
    for (int i = 0; i < 8; ++i) acc[i] = (f32x4){0.f, 0.f, 0.f, 0.f};

    int arow = r0 + lr;
    if (arow >= NN) arow = NN - 1;   // clamp (stores guarded)

#pragma unroll
    for (int kb = 0; kb < 4; ++kb) {
        int kofs = kb * 32 + lg * 8;
        short8 a = *(const short8*)(Sb + (size_t)arow * HD + kofs);
#pragma unroll
        for (int fr = 0; fr < 8; ++fr) {
            short8 b = *(const short8*)(Bw + (size_t)(fr * 16 + lr) * HD + kofs);
            acc[fr] = __builtin_amdgcn_mfma_f32_16x16x32_bf16(a, b, acc[fr], 0, 0, 0);
        }
    }

    float di[4];
#pragma unroll
    for (int j = 0; j < 4; ++j) {
        int grow = r0 + lg * 4 + j;
        di[j] = deg_inv[(grow < NN) ? grow : (NN - 1)];
    }
#pragma unroll
    for (int fr = 0; fr < 8; ++fr) {
        int col = fr * 16 + lr;
        float bs = bias[col];
        float me = 0.f, sc = 0.f, be = 0.f;
        if (MODE == 1) {
            me = bnm[col];
            sc = bng[col] * rsqrtf(bnv[col] + EPS_BN);
            be = bnb[col];
        }
#pragma unroll
        for (int j = 0; j < 4; ++j) {
            int grow = r0 + lg * 4 + j;
            if (grow >= NN) continue;
            float val = acc[fr][j] * di[j] + bs;
            if (MODE != 0) val += __bfloat162float(Ub[(size_t)grow * HD + col]);
            if (MODE == 1) {
                val = tanhf((val - me) * sc + be);
            }
            if (MODE == 2) {
                ((float*)out)[(size_t)grow * HD + col] = val;
            } else {
                ((__hip_bfloat16*)out)[(size_t)grow * HD + col] = __float2bfloat16(val);
            }
        }
    }
}

extern "C" void kernel_launch(void* const* d_in, const int* in_sizes, int n_in,
                              void* d_out, int out_size, void* d_ws, size_t ws_size,
                              hipStream_t stream) {
    const float* x   = (const float*)d_in[0];
    const int*   ei  = (const int*)d_in[1];
    const float* ea  = (const float*)d_in[2];
    const float* W0  = (const float*)d_in[3];
    const float* b0  = (const float*)d_in[4];
    const float* W1  = (const float*)d_in[5];
    const float* b1  = (const float*)d_in[6];
    const float* W2  = (const float*)d_in[7];
    const float* b2  = (const float*)d_in[8];
    const float* W3  = (const float*)d_in[9];
    const float* b3  = (const float*)d_in[10];
    const float* Wc  = (const float*)d_in[11];
    const float* bc  = (const float*)d_in[12];
    const float* bng = (const float*)d_in[13];
    const float* bnb = (const float*)d_in[14];
    const float* bnm = (const float*)d_in[15];
    const float* bnv = (const float*)d_in[16];

    const int* ei0 = ei;        // src
    const int* ei1 = ei + EE;   // dst

    char* ws = (char*)d_ws;
    int*   deg     = (int*)(ws + 0);                 // N*4
    int*   cursor  = (int*)(ws + 400000);            // N*4
    int*   counter = (int*)(ws + 800000);            // 4 (+pad)
    int*   off     = (int*)(ws + 800256);            // N*4
    float* deg_inv = (float*)(ws + 1200256);         // N*4 (+pad)
    __hip_bfloat16* Mb   = (__hip_bfloat16*)(ws + 1600512);   // 4*16384*2
    __hip_bfloat16* Wceb = (__hip_bfloat16*)(ws + 1731584);   // 16384*2
    int*   list_e  = (int*)(ws + 1764352);           // E*4
    int*   list_s  = (int*)(ws + 8164352);           // E*4
    unsigned* A_b  = (unsigned*)(ws + 14564352);     // N*128 bf16 = 25.6 MB
    unsigned* U_b  = (unsigned*)(ws + 40164352);     // N*128 bf16
    unsigned* S_b  = (unsigned*)(ws + 65764352);     // N*128 bf16
    unsigned* h_b  = (unsigned*)(ws + 91364352);     // N*128 bf16
    unsigned* x_b  = (unsigned*)(ws + 116964352);    // N*128 bf16  -> end ~142.6 MB
    (void)ws_size; (void)in_sizes; (void)n_in; (void)out_size;

    hipMemsetAsync(ws, 0, 800256, stream);  // deg, cursor, counter

    count_deg_k<<<(EE + 255) / 256, 256, 0, stream>>>(ei1, deg);
    alloc_off_k<<<(NN + 255) / 256, 256, 0, stream>>>(deg, off, deg_inv, counter);
    fill_csr_k<<<(EE + 255) / 256, 256, 0, stream>>>(ei0, ei1, off, cursor, list_e, list_s);

    conv_x_k<<<NN * HD / (256 * 8), 256, 0, stream>>>(x, x_b);
    agg_ea_k<<<NN / 4, 256, 0, stream>>>(ea, off, deg, list_e, A_b);
    prep_w_k<<<5 * 64, 256, 0, stream>>>(W0, W1, W2, W3, Wc, Mb, Wceb);

    int gblocks = (NN + 63) / 64;
    // U = (A @ Wce^T) * deg_inv + bc
    gemm_epi_k<0><<<gblocks, 256, 0, stream>>>((const __hip_bfloat16*)A_b, Wceb, nullptr,
                                               deg_inv, bc, nullptr, nullptr, nullptr, nullptr,
                                               (void*)U_b);

    const float* biases[4] = {b0, b1, b2, b3};
    for (int layer = 0; layer < 4; ++layer) {
        const unsigned* tab = (layer == 0) ? x_b : h_b;
        gather_sum_k<<<NN / 4, 256, 0, stream>>>(tab, off, deg, list_s, S_b);
        if (layer < 3) {
            gemm_epi_k<1><<<gblocks, 256, 0, stream>>>((const __hip_bfloat16*)S_b, Mb + layer * 16384,
                                                       (const __hip_bfloat16*)U_b, deg_inv, biases[layer],
                                                       bng, bnb, bnm, bnv, (void*)h_b);
        } else {
            gemm_epi_k<2><<<gblocks, 256, 0, stream>>>((const __hip_bfloat16*)S_b, Mb + layer * 16384,
                                                       (const __hip_bfloat16*)U_b, deg_inv, biases[layer],
                                                       nullptr, nullptr, nullptr, nullptr, d_out);
        }
    }
}

// Round 6
// 882.042 us; speedup vs baseline: 2.4191x; 1.0075x over previous
//
#include <hip/hip_runtime.h>
#include <hip/hip_bf16.h>
#include <math.h>

#define NN 100000
#define EE 1600000
#define HD 128
#define EPS_BN 1e-5f

typedef __attribute__((ext_vector_type(8))) short short8;   // 8 bf16 (4 VGPRs)
typedef __attribute__((ext_vector_type(4))) float f32x4;

__device__ inline float bf_hi(unsigned u) { return __uint_as_float(u & 0xffff0000u); }
__device__ inline float bf_lo(unsigned u) { return __uint_as_float(u << 16); }
__device__ inline unsigned pack_bf2(float x0, float x1) {
    __hip_bfloat16 a = __float2bfloat16(x0);
    __hip_bfloat16 b = __float2bfloat16(x1);
    unsigned short ua = *reinterpret_cast<unsigned short*>(&a);
    unsigned short ub = *reinterpret_cast<unsigned short*>(&b);
    return (unsigned)ua | ((unsigned)ub << 16);
}

// ---------------- CSR build ----------------
__global__ __launch_bounds__(256) void count_deg_k(const int* __restrict__ dst, int* __restrict__ deg) {
    int e = blockIdx.x * 256 + threadIdx.x;
    if (e < EE) atomicAdd(&deg[dst[e]], 1);
}

// wave-scan allocation: one atomic per wave, all lanes active for shfl safety
__global__ __launch_bounds__(256) void alloc_off_k(const int* __restrict__ deg, int* __restrict__ off,
                                                   float* __restrict__ deg_inv, int* __restrict__ counter) {
    int v = blockIdx.x * 256 + threadIdx.x;
    int lane = threadIdx.x & 63;
    int d = (v < NN) ? deg[v] : 0;
    int scan = d;
#pragma unroll
    for (int s = 1; s < 64; s <<= 1) {
        int t = __shfl_up(scan, s);
        if (lane >= s) scan += t;
    }
    int wave_total = __shfl(scan, 63);
    int base = 0;
    if (lane == 63) base = atomicAdd(counter, wave_total);
    base = __shfl(base, 63);
    if (v < NN) {
        off[v] = base + scan - d;
        deg_inv[v] = 1.0f / (float)(d + 1);   // +1 self-loop
    }
}

__global__ __launch_bounds__(256) void fill_csr_k(const int* __restrict__ src, const int* __restrict__ dst,
                                                  const int* __restrict__ off, int* __restrict__ cursor,
                                                  int* __restrict__ list_e, int* __restrict__ list_s) {
    int e = blockIdx.x * 256 + threadIdx.x;
    if (e < EE) {
        int v = dst[e];
        int p = atomicAdd(&cursor[v], 1);
        int q = off[v] + p;
        list_e[q] = e;
        list_s[q] = src[e];
    }
}

// ---------------- x -> bf16 ----------------
__global__ __launch_bounds__(256) void conv_x_k(const float* __restrict__ x, unsigned* __restrict__ xb) {
    int i = blockIdx.x * 256 + threadIdx.x;     // one thread = 8 floats
    size_t base = (size_t)i * 8;
    float4 a = *(const float4*)&x[base];
    float4 b = *(const float4*)&x[base + 4];
    uint4 w;
    w.x = pack_bf2(a.x, a.y); w.y = pack_bf2(a.z, a.w);
    w.z = pack_bf2(b.x, b.y); w.w = pack_bf2(b.z, b.w);
    *(uint4*)&xb[(size_t)i * 4] = w;
}

// ---------------- edge_attr aggregation: A[v] = sum ea[e], 4 chains/grp (direct loads) ----------------
__global__ __launch_bounds__(256) void agg_ea_k(const float* __restrict__ ea, const int* __restrict__ off,
                                                const int* __restrict__ deg, const int* __restrict__ list_e,
                                                unsigned* __restrict__ A) {   // bf16x2 packed [N][64]
    int v = blockIdx.x * 4 + (threadIdx.x >> 6);
    int lane = threadIdx.x & 63;
    int grp = lane >> 5, lr = lane & 31;     // lr covers floats lr*4..+3 of a 512B row
    if (v >= NN) return;
    int o = off[v], d = deg[v];
    float a0 = 0.f, a1 = 0.f, a2 = 0.f, a3 = 0.f;
    float c0 = 0.f, c1 = 0.f, c2 = 0.f, c3 = 0.f;
    int j = grp;
    for (; j + 6 < d; j += 8) {
        int e0 = list_e[o + j];
        int e1 = list_e[o + j + 2];
        int e2 = list_e[o + j + 4];
        int e3 = list_e[o + j + 6];
        float4 r0 = *(const float4*)&ea[(size_t)e0 * HD + lr * 4];
        float4 r1 = *(const float4*)&ea[(size_t)e1 * HD + lr * 4];
        float4 r2 = *(const float4*)&ea[(size_t)e2 * HD + lr * 4];
        float4 r3 = *(const float4*)&ea[(size_t)e3 * HD + lr * 4];
        a0 += r0.x + r1.x; a1 += r0.y + r1.y; a2 += r0.z + r1.z; a3 += r0.w + r1.w;
        c0 += r2.x + r3.x; c1 += r2.y + r3.y; c2 += r2.z + r3.z; c3 += r2.w + r3.w;
    }
    for (; j + 2 < d; j += 4) {
        int e0 = list_e[o + j];
        int e1 = list_e[o + j + 2];
        float4 r0 = *(const float4*)&ea[(size_t)e0 * HD + lr * 4];
        float4 r1 = *(const float4*)&ea[(size_t)e1 * HD + lr * 4];
        a0 += r0.x + r1.x; a1 += r0.y + r1.y; a2 += r0.z + r1.z; a3 += r0.w + r1.w;
    }
    for (; j < d; j += 2) {
        int e = list_e[o + j];
        float4 r = *(const float4*)&ea[(size_t)e * HD + lr * 4];
        a0 += r.x; a1 += r.y; a2 += r.z; a3 += r.w;
    }
    a0 += c0; a1 += c1; a2 += c2; a3 += c3;
    a0 += __shfl_xor(a0, 32); a1 += __shfl_xor(a1, 32);
    a2 += __shfl_xor(a2, 32); a3 += __shfl_xor(a3, 32);
    if (grp == 0) {
        uint2 w;
        w.x = pack_bf2(a0, a1); w.y = pack_bf2(a2, a3);
        *(uint2*)&A[(size_t)v * 64 + lr * 2] = w;
    }
}

// ---------------- neighbor sum S[v] = tab[v] + sum tab[src], 4 chains/grp (direct loads) ----------------
__global__ __launch_bounds__(256) void gather_sum_k(const unsigned* __restrict__ tab,  // bf16x2 [N][64]
                                                    const int* __restrict__ off, const int* __restrict__ deg,
                                                    const int* __restrict__ list_s,
                                                    unsigned* __restrict__ S) {
    int v = blockIdx.x * 4 + (threadIdx.x >> 6);
    int lane = threadIdx.x & 63;
    int grp = lane >> 4, lr = lane & 15;     // lr covers uints lr*4..+3 (channels lr*8..+7)
    if (v >= NN) return;
    int o = off[v], d = deg[v];
    float acc[8], acc2[8];
    {   // self row (count once: grp 0 only)
        uint4 r = *(const uint4*)&tab[(size_t)v * 64 + lr * 4];
        bool m = (grp == 0);
        acc[0] = m ? bf_lo(r.x) : 0.f; acc[1] = m ? bf_hi(r.x) : 0.f;
        acc[2] = m ? bf_lo(r.y) : 0.f; acc[3] = m ? bf_hi(r.y) : 0.f;
        acc[4] = m ? bf_lo(r.z) : 0.f; acc[5] = m ? bf_hi(r.z) : 0.f;
        acc[6] = m ? bf_lo(r.w) : 0.f; acc[7] = m ? bf_hi(r.w) : 0.f;
    }
#pragma unroll
    for (int i = 0; i < 8; ++i) acc2[i] = 0.f;
    int j = grp;
    for (; j + 12 < d; j += 16) {
        int s0 = list_s[o + j];
        int s1 = list_s[o + j + 4];
        int s2 = list_s[o + j + 8];
        int s3 = list_s[o + j + 12];
        uint4 r0 = *(const uint4*)&tab[(size_t)s0 * 64 + lr * 4];
        uint4 r1 = *(const uint4*)&tab[(size_t)s1 * 64 + lr * 4];
        uint4 r2 = *(const uint4*)&tab[(size_t)s2 * 64 + lr * 4];
        uint4 r3 = *(const uint4*)&tab[(size_t)s3 * 64 + lr * 4];
        acc[0] += bf_lo(r0.x) + bf_lo(r1.x); acc[1] += bf_hi(r0.x) + bf_hi(r1.x);
        acc[2] += bf_lo(r0.y) + bf_lo(r1.y); acc[3] += bf_hi(r0.y) + bf_hi(r1.y);
        acc[4] += bf_lo(r0.z) + bf_lo(r1.z); acc[5] += bf_hi(r0.z) + bf_hi(r1.z);
        acc[6] += bf_lo(r0.w) + bf_lo(r1.w); acc[7] += bf_hi(r0.w) + bf_hi(r1.w);
        acc2[0] += bf_lo(r2.x) + bf_lo(r3.x); acc2[1] += bf_hi(r2.x) + bf_hi(r3.x);
        acc2[2] += bf_lo(r2.y) + bf_lo(r3.y); acc2[3] += bf_hi(r2.y) + bf_hi(r3.y);
        acc2[4] += bf_lo(r2.z) + bf_lo(r3.z); acc2[5] += bf_hi(r2.z) + bf_hi(r3.z);
        acc2[6] += bf_lo(r2.w) + bf_lo(r3.w); acc2[7] += bf_hi(r2.w) + bf_hi(r3.w);
    }
    for (; j + 4 < d; j += 8) {
        int s0 = list_s[o + j];
        int s1 = list_s[o + j + 4];
        uint4 r0 = *(const uint4*)&tab[(size_t)s0 * 64 + lr * 4];
        uint4 r1 = *(const uint4*)&tab[(size_t)s1 * 64 + lr * 4];
        acc[0] += bf_lo(r0.x) + bf_lo(r1.x); acc[1] += bf_hi(r0.x) + bf_hi(r1.x);
        acc[2] += bf_lo(r0.y) + bf_lo(r1.y); acc[3] += bf_hi(r0.y) + bf_hi(r1.y);
        acc[4] += bf_lo(r0.z) + bf_lo(r1.z); acc[5] += bf_hi(r0.z) + bf_hi(r1.z);
        acc[6] += bf_lo(r0.w) + bf_lo(r1.w); acc[7] += bf_hi(r0.w) + bf_hi(r1.w);
    }
    for (; j < d; j += 4) {
        int s = list_s[o + j];
        uint4 r = *(const uint4*)&tab[(size_t)s * 64 + lr * 4];
        acc[0] += bf_lo(r.x); acc[1] += bf_hi(r.x);
        acc[2] += bf_lo(r.y); acc[3] += bf_hi(r.y);
        acc[4] += bf_lo(r.z); acc[5] += bf_hi(r.z);
        acc[6] += bf_lo(r.w); acc[7] += bf_hi(r.w);
    }
#pragma unroll
    for (int i = 0; i < 8; ++i) {
        acc[i] += acc2[i];
        acc[i] += __shfl_xor(acc[i], 16);
        acc[i] += __shfl_xor(acc[i], 32);
    }
    if (grp == 0) {
        uint4 w;
        w.x = pack_bf2(acc[0], acc[1]); w.y = pack_bf2(acc[2], acc[3]);
        w.z = pack_bf2(acc[4], acc[5]); w.w = pack_bf2(acc[6], acc[7]);
        *(uint4*)&S[(size_t)v * 64 + lr * 4] = w;
    }
}

// ---------------- weights prep: M_i = Wc_h @ W_i (bf16), Wce (bf16) ----------------
__global__ __launch_bounds__(256) void prep_w_k(const float* __restrict__ W0, const float* __restrict__ W1,
                                                const float* __restrict__ W2, const float* __restrict__ W3,
                                                const float* __restrict__ Wc,
                                                __hip_bfloat16* __restrict__ Mb,
                                                __hip_bfloat16* __restrict__ Wceb) {
    int part = blockIdx.x >> 6;                       // 0..4
    int idx = ((blockIdx.x & 63) << 8) + threadIdx.x; // 0..16383
    int o = idx >> 7, k = idx & 127;
    if (part < 4) {
        const float* W = (part == 0) ? W0 : (part == 1) ? W1 : (part == 2) ? W2 : W3;
        float s = 0.f;
        for (int j = 0; j < 128; ++j) s += Wc[o * 256 + j] * W[j * 128 + k];
        Mb[part * 16384 + idx] = __float2bfloat16(s);
    } else {
        Wceb[idx] = __float2bfloat16(Wc[o * 256 + 128 + k]);
    }
}

// ---------------- MFMA GEMM with fused epilogue ----------------
// out = epi( (Sb @ Bw^T) ) per MODE:
//   MODE 0: val*di + bias               -> bf16 out   (U build)
//   MODE 1: tanh(BN(val*di + U + bias)) -> bf16 out   (mid layer)
//   MODE 2: val*di + U + bias           -> f32 out    (last layer)
template <int MODE>
__global__ __launch_bounds__(256) void gemm_epi_k(const __hip_bfloat16* __restrict__ Sb,
                                                  const __hip_bfloat16* __restrict__ Bw,
                                                  const __hip_bfloat16* __restrict__ Ub,
                                                  const float* __restrict__ deg_inv,
                                                  const float* __restrict__ bias,
                                                  const float* __restrict__ bng, const float* __restrict__ bnb,
                                                  const float* __restrict__ bnm, const float* __restrict__ bnv,
                                                  void* __restrict__ out) {
    int wave = threadIdx.x >> 6, lane = threadIdx.x & 63;
    int r0 = blockIdx.x * 64 + wave * 16;
    int lr = lane & 15, lg = lane >> 4;

    f32x4 acc[8];
#pragma unroll
    for (int i = 0; i < 8; ++i) acc[i] = (f32x4){0.f, 0.f, 0.f, 0.f};

    int arow = r0 + lr;
    if (arow >= NN) arow = NN - 1;   // clamp (stores guarded)

#pragma unroll
    for (int kb = 0; kb < 4; ++kb) {
        int kofs = kb * 32 + lg * 8;
        short8 a = *(const short8*)(Sb + (size_t)arow * HD + kofs);
#pragma unroll
        for (int fr = 0; fr < 8; ++fr) {
            short8 b = *(const short8*)(Bw + (size_t)(fr * 16 + lr) * HD + kofs);
            acc[fr] = __builtin_amdgcn_mfma_f32_16x16x32_bf16(a, b, acc[fr], 0, 0, 0);
        }
    }

    float di[4];
#pragma unroll
    for (int j = 0; j < 4; ++j) {
        int grow = r0 + lg * 4 + j;
        di[j] = deg_inv[(grow < NN) ? grow : (NN - 1)];
    }
#pragma unroll
    for (int fr = 0; fr < 8; ++fr) {
        int col = fr * 16 + lr;
        float bs = bias[col];
        float me = 0.f, sc = 0.f, be = 0.f;
        if (MODE == 1) {
            me = bnm[col];
            sc = bng[col] * rsqrtf(bnv[col] + EPS_BN);
            be = bnb[col];
        }
#pragma unroll
        for (int j = 0; j < 4; ++j) {
            int grow = r0 + lg * 4 + j;
            if (grow >= NN) continue;
            float val = acc[fr][j] * di[j] + bs;
            if (MODE != 0) val += __bfloat162float(Ub[(size_t)grow * HD + col]);
            if (MODE == 1) {
                val = tanhf((val - me) * sc + be);
            }
            if (MODE == 2) {
                ((float*)out)[(size_t)grow * HD + col] = val;
            } else {
                ((__hip_bfloat16*)out)[(size_t)grow * HD + col] = __float2bfloat16(val);
            }
        }
    }
}

extern "C" void kernel_launch(void* const* d_in, const int* in_sizes, int n_in,
                              void* d_out, int out_size, void* d_ws, size_t ws_size,
                              hipStream_t stream) {
    const float* x   = (const float*)d_in[0];
    const int*   ei  = (const int*)d_in[1];
    const float* ea  = (const float*)d_in[2];
    const float* W0  = (const float*)d_in[3];
    const float* b0  = (const float*)d_in[4];
    const float* W1  = (const float*)d_in[5];
    const float* b1  = (const float*)d_in[6];
    const float* W2  = (const float*)d_in[7];
    const float* b2  = (const float*)d_in[8];
    const float* W3  = (const float*)d_in[9];
    const float* b3  = (const float*)d_in[10];
    const float* Wc  = (const float*)d_in[11];
    const float* bc  = (const float*)d_in[12];
    const float* bng = (const float*)d_in[13];
    const float* bnb = (const float*)d_in[14];
    const float* bnm = (const float*)d_in[15];
    const float* bnv = (const float*)d_in[16];

    const int* ei0 = ei;        // src
    const int* ei1 = ei + EE;   // dst

    char* ws = (char*)d_ws;
    int*   deg     = (int*)(ws + 0);                 // N*4
    int*   cursor  = (int*)(ws + 400000);            // N*4
    int*   counter = (int*)(ws + 800000);            // 4 (+pad)
    int*   off     = (int*)(ws + 800256);            // N*4
    float* deg_inv = (float*)(ws + 1200256);         // N*4 (+pad)
    __hip_bfloat16* Mb   = (__hip_bfloat16*)(ws + 1600512);   // 4*16384*2
    __hip_bfloat16* Wceb = (__hip_bfloat16*)(ws + 1731584);   // 16384*2
    int*   list_e  = (int*)(ws + 1764352);           // E*4
    int*   list_s  = (int*)(ws + 8164352);           // E*4
    unsigned* A_b  = (unsigned*)(ws + 14564352);     // N*128 bf16 = 25.6 MB
    unsigned* U_b  = (unsigned*)(ws + 40164352);     // N*128 bf16
    unsigned* S_b  = (unsigned*)(ws + 65764352);     // N*128 bf16
    unsigned* h_b  = (unsigned*)(ws + 91364352);     // N*128 bf16
    unsigned* x_b  = (unsigned*)(ws + 116964352);    // N*128 bf16  -> end ~142.6 MB
    (void)ws_size; (void)in_sizes; (void)n_in; (void)out_size;

    hipMemsetAsync(ws, 0, 800256, stream);  // deg, cursor, counter

    count_deg_k<<<(EE + 255) / 256, 256, 0, stream>>>(ei1, deg);
    alloc_off_k<<<(NN + 255) / 256, 256, 0, stream>>>(deg, off, deg_inv, counter);
    fill_csr_k<<<(EE + 255) / 256, 256, 0, stream>>>(ei0, ei1, off, cursor, list_e, list_s);

    conv_x_k<<<NN * HD / (256 * 8), 256, 0, stream>>>(x, x_b);
    agg_ea_k<<<NN / 4, 256, 0, stream>>>(ea, off, deg, list_e, A_b);
    prep_w_k<<<5 * 64, 256, 0, stream>>>(W0, W1, W2, W3, Wc, Mb, Wceb);

    int gblocks = (NN + 63) / 64;
    // U = (A @ Wce^T) * deg_inv + bc
    gemm_epi_k<0><<<gblocks, 256, 0, stream>>>((const __hip_bfloat16*)A_b, Wceb, nullptr,
                                               deg_inv, bc, nullptr, nullptr, nullptr, nullptr,
                                               (void*)U_b);

    const float* biases[4] = {b0, b1, b2, b3};
    for (int layer = 0; layer < 4; ++layer) {
        const unsigned* tab = (layer == 0) ? x_b : h_b;
        gather_sum_k<<<NN / 4, 256, 0, stream>>>(tab, off, deg, list_s, S_b);
        if (layer < 3) {
            gemm_epi_k<1><<<gblocks, 256, 0, stream>>>((const __hip_bfloat16*)S_b, Mb + layer * 16384,
                                                       (const __hip_bfloat16*)U_b, deg_inv, biases[layer],
                                                       bng, bnb, bnm, bnv, (void*)h_b);
        } else {
            gemm_epi_k<2><<<gblocks, 256, 0, stream>>>((const __hip_bfloat16*)S_b, Mb + layer * 16384,
                                                       (const __hip_bfloat16*)U_b, deg_inv, biases[layer],
                                                       nullptr, nullptr, nullptr, nullptr, d_out);
        }
    }
}